// Round 9
// baseline (563.153 us; speedup 1.0000x reference)
//
#include <hip/hip_runtime.h>
#include <math.h>

#define B 8
#define P 512
#define C 1024
#define H 8
#define BN_EPS 1e-5f

typedef __attribute__((ext_vector_type(8))) __bf16 bf16x8;
typedef __attribute__((ext_vector_type(4))) __bf16 bf16x4;
typedef __attribute__((ext_vector_type(4))) float f32x4;
typedef __attribute__((ext_vector_type(4))) short short4v;

static __device__ __forceinline__ short4v bc4(bf16x4 v) {
    short4v r; __builtin_memcpy(&r, &v, 8); return r;
}

// ---------------------------------------------------------------------------
// Kernel 0: split x (B,P,C) and W (C,C) into hi/lo bf16. One float4/thread.
// ---------------------------------------------------------------------------
__global__ __launch_bounds__(256) void split_hi_lo(
    const float* __restrict__ x, const float* __restrict__ Wq,
    __bf16* __restrict__ xhi, __bf16* __restrict__ xlo,
    __bf16* __restrict__ whi, __bf16* __restrict__ wlo)
{
    const size_t NX4 = (size_t)B * P * C / 4;
    size_t idx = (size_t)blockIdx.x * 256 + threadIdx.x;
    float4 v;
    __bf16 *dh, *dl;
    size_t o;
    if (idx < NX4) {
        v = ((const float4*)x)[idx];
        dh = xhi; dl = xlo; o = idx * 4;
    } else {
        v = ((const float4*)Wq)[idx - NX4];
        dh = whi; dl = wlo; o = (idx - NX4) * 4;
    }
    float f[4] = {v.x, v.y, v.z, v.w};
    bf16x4 hv, lv;
    #pragma unroll
    for (int j = 0; j < 4; ++j) {
        __bf16 hb = (__bf16)f[j];
        hv[j] = hb;
        lv[j] = (__bf16)(f[j] - (float)hb);
    }
    *(bf16x4*)&dh[o] = hv;
    *(bf16x4*)&dl[o] = lv;
}

// ---------------------------------------------------------------------------
// Kernel 1: Y[b,d,p] = BN( sum_c W[d,c] * x[b,p,c] ) via split-bf16 MFMA.
// (unchanged — proven)
// ---------------------------------------------------------------------------
__global__ __launch_bounds__(256) void qkv_bn_mfma(
    const __bf16* __restrict__ xhi, const __bf16* __restrict__ xlo,
    const __bf16* __restrict__ whi, const __bf16* __restrict__ wlo,
    const float* __restrict__ gamma, const float* __restrict__ beta,
    const float* __restrict__ mean, const float* __restrict__ var,
    __bf16* __restrict__ Yhi, __bf16* __restrict__ Ylo, __bf16* __restrict__ Zhi)
{
    const int dt = blockIdx.x;   // 16
    const int pt = blockIdx.y;   // 8
    const int b  = blockIdx.z;   // 8
    const int t = threadIdx.x, lane = t & 63, wid = t >> 6;
    const int quadd = (wid >> 1) * 32, quadp = (wid & 1) * 32;
    const int lr = lane & 15, lk = (lane >> 4) * 8;

    const int drow0 = dt * 64 + quadd + lr;
    const size_t xrow0 = ((size_t)b * P + pt * 64 + quadp + lr) * C;

    f32x4 acc[2][2];
    #pragma unroll
    for (int tm = 0; tm < 2; ++tm)
        #pragma unroll
        for (int tn = 0; tn < 2; ++tn)
            acc[tm][tn] = (f32x4){0.f, 0.f, 0.f, 0.f};

    for (int c0 = 0; c0 < C; c0 += 32) {
        const int col = c0 + lk;
        bf16x8 ah[2], al[2], bh[2], bl[2];
        #pragma unroll
        for (int tm = 0; tm < 2; ++tm) {
            size_t ia = (size_t)(drow0 + tm * 16) * C + col;
            ah[tm] = *(const bf16x8*)&whi[ia];
            al[tm] = *(const bf16x8*)&wlo[ia];
        }
        #pragma unroll
        for (int tn = 0; tn < 2; ++tn) {
            size_t ib = xrow0 + (size_t)tn * 16 * C + col;
            bh[tn] = *(const bf16x8*)&xhi[ib];
            bl[tn] = *(const bf16x8*)&xlo[ib];
        }
        #pragma unroll
        for (int tm = 0; tm < 2; ++tm)
            #pragma unroll
            for (int tn = 0; tn < 2; ++tn) {
                acc[tm][tn] = __builtin_amdgcn_mfma_f32_16x16x32_bf16(ah[tm], bh[tn], acc[tm][tn], 0, 0, 0);
                acc[tm][tn] = __builtin_amdgcn_mfma_f32_16x16x32_bf16(ah[tm], bl[tn], acc[tm][tn], 0, 0, 0);
                acc[tm][tn] = __builtin_amdgcn_mfma_f32_16x16x32_bf16(al[tm], bh[tn], acc[tm][tn], 0, 0, 0);
            }
    }

    const int rgrp = (lane >> 4) * 4;
    #pragma unroll
    for (int tm = 0; tm < 2; ++tm) {
        const int dbase = dt * 64 + quadd + tm * 16 + rgrp;
        float4 g4 = *(const float4*)&gamma[dbase];
        float4 bb4 = *(const float4*)&beta[dbase];
        float4 m4 = *(const float4*)&mean[dbase];
        float4 v4 = *(const float4*)&var[dbase];
        float gf[4] = {g4.x, g4.y, g4.z, g4.w};
        float bf[4] = {bb4.x, bb4.y, bb4.z, bb4.w};
        float mf[4] = {m4.x, m4.y, m4.z, m4.w};
        float vf[4] = {v4.x, v4.y, v4.z, v4.w};
        float sc[4];
        #pragma unroll
        for (int r = 0; r < 4; ++r) sc[r] = rsqrtf(vf[r] + BN_EPS) * gf[r];

        #pragma unroll
        for (int tn = 0; tn < 2; ++tn) {
            const int p = pt * 64 + quadp + tn * 16 + lr;
            bf16x4 zq;
            #pragma unroll
            for (int r = 0; r < 4; ++r) {
                float n = (acc[tm][tn][r] - mf[r]) * sc[r] + bf[r];
                __bf16 hb = (__bf16)n;
                __bf16 lb = (__bf16)(n - (float)hb);
                size_t yi = ((size_t)b * C + dbase + r) * P + p;
                Yhi[yi] = hb;
                Ylo[yi] = lb;
                zq[r] = hb;
            }
            *(bf16x4*)&Zhi[((size_t)b * P + p) * C + dbase] = zq;
        }
    }
}

// ---------------------------------------------------------------------------
// Kernel 2 (FUSED v5): round-8 structure + raw per-it s_barrier (wave timing
// alignment WITHOUT memory drain) + full c-side register hoist.
// Grid 512: b = id&7 (XCD pin), ct = id>>3 (64 c-tiles of 16). 4 waves.
// Per it: wave w owns d-slice dwin = it*64 + w*16 — block covers one 64-d
// window simultaneously; the raw barrier keeps waves within ~1 it of each
// other so attn L2 lines are assembled promptly (round-6 write behavior).
// Scores SWAPPED (A = d-side, B = c-side): softmax'd P fragment in registers
// IS the K=16 MFMA B-operand. PV register-resident, no LDS for P.
// attn writes coalesced via wave-private 16x16 LDS transpose (no barrier).
// ---------------------------------------------------------------------------
__global__ __launch_bounds__(256, 2) void attn_fused(
    const __bf16* __restrict__ Yhi, const __bf16* __restrict__ Ylo,
    const __bf16* __restrict__ Zhi, const float* __restrict__ gs_ptr,
    float* __restrict__ attn, float* __restrict__ out0)
{
    const int id = blockIdx.x;
    const int b  = id & 7;            // XCD pin (dispatch round-robins XCDs)
    const int ct = id >> 3;           // 0..63
    const int c0 = ct * 16;
    const int t = threadIdx.x, lane = t & 63, w = t >> 6;
    const int lc = lane & 15;         // c offset (scores N / PV N), p row (PV A)
    const int lg = lane >> 4;
    const int lk = lg * 8;            // K=32 k-offset
    const int rgrp = lg * 4;          // accumulator row group / K=16 k-offset
    const float scale = 1.0f / gs_ptr[0];

    __shared__ __align__(16) float Tbuf[4][16][20];   // 5 KB wave-private transpose
    __shared__ __align__(16) float cb[4][4][64][4];   // 16 KB final combine

    // ---- hoist loop-invariant c-side fragments (hi AND lo) ----
    const size_t cbase = ((size_t)b * C + c0 + lc) * P;
    bf16x8 chh[16], cll[16];
    #pragma unroll
    for (int h = 0; h < H; ++h)
        #pragma unroll
        for (int s = 0; s < 2; ++s) {
            const int col = h * 64 + s * 32 + lk;
            chh[h * 2 + s] = *(const bf16x8*)&Yhi[cbase + col];
            cll[h * 2 + s] = *(const bf16x8*)&Ylo[cbase + col];
        }

    f32x4 out_acc[8][4];              // [h][p-tile of 16] — partial over d
    #pragma unroll
    for (int h = 0; h < H; ++h)
        #pragma unroll
        for (int pt = 0; pt < 4; ++pt)
            out_acc[h][pt] = (f32x4){0.f, 0.f, 0.f, 0.f};

    for (int it = 0; it < 16; ++it) {
        // timing-alignment barrier only: no memory drain, LDS is wave-private
        __builtin_amdgcn_s_barrier();

        const int dwin = it * 64 + w * 16;                 // this wave's d-slice
        const size_t dbase = ((size_t)b * C + dwin + lc) * P;  // d-side row (A)

        // ---- scores^T: 16d x 16c per head, 3-product split ----
        f32x4 sacc[8];
        #pragma unroll
        for (int h = 0; h < H; ++h) sacc[h] = (f32x4){0.f, 0.f, 0.f, 0.f};

        #pragma unroll
        for (int h = 0; h < H; ++h) {
            #pragma unroll
            for (int s = 0; s < 2; ++s) {
                const int col = h * 64 + s * 32 + lk;
                bf16x8 dh_ = *(const bf16x8*)&Yhi[dbase + col];
                bf16x8 dl_ = *(const bf16x8*)&Ylo[dbase + col];
                sacc[h] = __builtin_amdgcn_mfma_f32_16x16x32_bf16(dh_, chh[h * 2 + s], sacc[h], 0, 0, 0);
                sacc[h] = __builtin_amdgcn_mfma_f32_16x16x32_bf16(dh_, cll[h * 2 + s], sacc[h], 0, 0, 0);
                sacc[h] = __builtin_amdgcn_mfma_f32_16x16x32_bf16(dl_, chh[h * 2 + s], sacc[h], 0, 0, 0);
            }
        }

        // ---- head-softmax per (c,d): c = c0+lc, d = dwin + rgrp + r ----
        #pragma unroll
        for (int r = 0; r < 4; ++r) {
            float v[8];
            float m = -1e30f;
            #pragma unroll
            for (int h = 0; h < H; ++h) {
                v[h] = sacc[h][r] * scale;
                m = fmaxf(m, v[h]);
            }
            float ssum = 0.f;
            #pragma unroll
            for (int h = 0; h < H; ++h) { v[h] = __expf(v[h] - m); ssum += v[h]; }
            float inv = 1.0f / ssum;
            #pragma unroll
            for (int h = 0; h < H; ++h) sacc[h][r] = v[h] * inv;
        }

        // ---- per head: coalesced attn write (wave-private transpose) + PV ----
        const int cpr = lane >> 2;           // 0..15: c for the attn store
        const int dpr = (lane & 3) * 4;      // 0,4,8,12: d for the attn store
        #pragma unroll
        for (int h = 0; h < H; ++h) {
            // attn[c][d] transpose through LDS (in-wave, no barrier)
            *(f32x4*)&Tbuf[w][lc][rgrp] = sacc[h];
            f32x4 av_ = *(const f32x4*)&Tbuf[w][cpr][dpr];
            *(f32x4*)&attn[(((size_t)(b * H + h) * C) + c0 + cpr) * C + dwin + dpr] = av_;

            // P -> bf16: register fragment IS the K=16 B-operand
            bf16x4 pq;
            #pragma unroll
            for (int r = 0; r < 4; ++r) pq[r] = (__bf16)sacc[h][r];
            short4v pb = bc4(pq);

            #pragma unroll
            for (int pt = 0; pt < 4; ++pt) {
                bf16x4 vv = *(const bf16x4*)&Zhi[((size_t)b * P + h * 64 + pt * 16 + lc) * C + dwin + rgrp];
                out_acc[h][pt] = __builtin_amdgcn_mfma_f32_16x16x16bf16_1k(
                    bc4(vv), pb, out_acc[h][pt], 0, 0, 0);
            }
        }
    }

    // ---- final combine across the 4 d-slice waves, then store out0 ----
    __syncthreads();
    for (int h = 0; h < H; ++h) {
        #pragma unroll
        for (int pt = 0; pt < 4; ++pt)
            *(f32x4*)&cb[w][pt][lane][0] = out_acc[h][pt];
        __syncthreads();
        f32x4 s = (f32x4){0.f, 0.f, 0.f, 0.f};
        #pragma unroll
        for (int w2 = 0; w2 < 4; ++w2)
            s += *(const f32x4*)&cb[w2][w][lane][0];
        #pragma unroll
        for (int r = 0; r < 4; ++r)
            out0[((size_t)b * P + h * 64 + w * 16 + rgrp + r) * C + c0 + lc] = s[r];
        __syncthreads();
    }
}

extern "C" void kernel_launch(void* const* d_in, const int* in_sizes, int n_in,
                              void* d_out, int out_size, void* d_ws, size_t ws_size,
                              hipStream_t stream) {
    const float* x     = (const float*)d_in[0];
    const float* Wq    = (const float*)d_in[1];
    const float* gamma = (const float*)d_in[2];
    const float* beta  = (const float*)d_in[3];
    const float* mean  = (const float*)d_in[4];
    const float* var   = (const float*)d_in[5];
    const float* gs    = (const float*)d_in[6];

    float* out0 = (float*)d_out;                          // h: (B,P,C)
    float* attn = (float*)d_out + (size_t)B * P * C;      // attn: (B,H,C,C)

    const size_t NE = (size_t)B * C * P;                  // 4M elements
    __bf16* Yhi = (__bf16*)d_ws;                          // 8 MB
    __bf16* Ylo = Yhi + NE;                               // 8 MB
    __bf16* Zhi = Ylo + NE;                               // 8 MB

    // transient scratch in the attn-region tail (dead before attn is written)
    const size_t attn_elems = (size_t)B * H * C * C;
    __bf16* S = (__bf16*)(attn + (attn_elems - 5242880));
    __bf16* xhi = S;
    __bf16* xlo = xhi + (size_t)B * P * C;
    __bf16* whi = xlo + (size_t)B * P * C;
    __bf16* wlo = whi + (size_t)C * C;

    split_hi_lo<<<5120, 256, 0, stream>>>(x, Wq, xhi, xlo, whi, wlo);
    qkv_bn_mfma<<<dim3(16, 8, 8), 256, 0, stream>>>(xhi, xlo, whi, wlo,
                                                    gamma, beta, mean, var,
                                                    Yhi, Ylo, Zhi);
    attn_fused<<<512, 256, 0, stream>>>(Yhi, Ylo, Zhi, gs, attn, out0);
}

// Round 10
// 539.829 us; speedup vs baseline: 1.0432x; 1.0432x over previous
//
#include <hip/hip_runtime.h>
#include <math.h>

#define B 8
#define P 512
#define C 1024
#define H 8
#define BN_EPS 1e-5f

typedef __attribute__((ext_vector_type(8))) __bf16 bf16x8;
typedef __attribute__((ext_vector_type(4))) __bf16 bf16x4;
typedef __attribute__((ext_vector_type(4))) float f32x4;

// ---------------------------------------------------------------------------
// Kernel 0: split x (B,P,C) and W (C,C) into hi/lo bf16. One float4/thread.
// ---------------------------------------------------------------------------
__global__ __launch_bounds__(256) void split_hi_lo(
    const float* __restrict__ x, const float* __restrict__ Wq,
    __bf16* __restrict__ xhi, __bf16* __restrict__ xlo,
    __bf16* __restrict__ whi, __bf16* __restrict__ wlo)
{
    const size_t NX4 = (size_t)B * P * C / 4;
    size_t idx = (size_t)blockIdx.x * 256 + threadIdx.x;
    float4 v;
    __bf16 *dh, *dl;
    size_t o;
    if (idx < NX4) {
        v = ((const float4*)x)[idx];
        dh = xhi; dl = xlo; o = idx * 4;
    } else {
        v = ((const float4*)Wq)[idx - NX4];
        dh = whi; dl = wlo; o = (idx - NX4) * 4;
    }
    float f[4] = {v.x, v.y, v.z, v.w};
    bf16x4 hv, lv;
    #pragma unroll
    for (int j = 0; j < 4; ++j) {
        __bf16 hb = (__bf16)f[j];
        hv[j] = hb;
        lv[j] = (__bf16)(f[j] - (float)hb);
    }
    *(bf16x4*)&dh[o] = hv;
    *(bf16x4*)&dl[o] = lv;
}

// ---------------------------------------------------------------------------
// Kernel 0b: zero out0 (needed: attn_fused accumulates with atomics).
// ---------------------------------------------------------------------------
__global__ __launch_bounds__(256) void zero_out0(float* __restrict__ out0)
{
    size_t i = ((size_t)blockIdx.x * 256 + threadIdx.x) * 4;
    *(f32x4*)&out0[i] = (f32x4){0.f, 0.f, 0.f, 0.f};
}

// ---------------------------------------------------------------------------
// Kernel 1: Y[b,d,p] = BN( sum_c W[d,c] * x[b,p,c] ) via split-bf16 MFMA.
// (unchanged — proven)
// ---------------------------------------------------------------------------
__global__ __launch_bounds__(256) void qkv_bn_mfma(
    const __bf16* __restrict__ xhi, const __bf16* __restrict__ xlo,
    const __bf16* __restrict__ whi, const __bf16* __restrict__ wlo,
    const float* __restrict__ gamma, const float* __restrict__ beta,
    const float* __restrict__ mean, const float* __restrict__ var,
    __bf16* __restrict__ Yhi, __bf16* __restrict__ Ylo, __bf16* __restrict__ Zhi)
{
    const int dt = blockIdx.x;   // 16
    const int pt = blockIdx.y;   // 8
    const int b  = blockIdx.z;   // 8
    const int t = threadIdx.x, lane = t & 63, wid = t >> 6;
    const int quadd = (wid >> 1) * 32, quadp = (wid & 1) * 32;
    const int lr = lane & 15, lk = (lane >> 4) * 8;

    const int drow0 = dt * 64 + quadd + lr;
    const size_t xrow0 = ((size_t)b * P + pt * 64 + quadp + lr) * C;

    f32x4 acc[2][2];
    #pragma unroll
    for (int tm = 0; tm < 2; ++tm)
        #pragma unroll
        for (int tn = 0; tn < 2; ++tn)
            acc[tm][tn] = (f32x4){0.f, 0.f, 0.f, 0.f};

    for (int c0 = 0; c0 < C; c0 += 32) {
        const int col = c0 + lk;
        bf16x8 ah[2], al[2], bh[2], bl[2];
        #pragma unroll
        for (int tm = 0; tm < 2; ++tm) {
            size_t ia = (size_t)(drow0 + tm * 16) * C + col;
            ah[tm] = *(const bf16x8*)&whi[ia];
            al[tm] = *(const bf16x8*)&wlo[ia];
        }
        #pragma unroll
        for (int tn = 0; tn < 2; ++tn) {
            size_t ib = xrow0 + (size_t)tn * 16 * C + col;
            bh[tn] = *(const bf16x8*)&xhi[ib];
            bl[tn] = *(const bf16x8*)&xlo[ib];
        }
        #pragma unroll
        for (int tm = 0; tm < 2; ++tm)
            #pragma unroll
            for (int tn = 0; tn < 2; ++tn) {
                acc[tm][tn] = __builtin_amdgcn_mfma_f32_16x16x32_bf16(ah[tm], bh[tn], acc[tm][tn], 0, 0, 0);
                acc[tm][tn] = __builtin_amdgcn_mfma_f32_16x16x32_bf16(ah[tm], bl[tn], acc[tm][tn], 0, 0, 0);
                acc[tm][tn] = __builtin_amdgcn_mfma_f32_16x16x32_bf16(al[tm], bh[tn], acc[tm][tn], 0, 0, 0);
            }
    }

    const int rgrp = (lane >> 4) * 4;
    #pragma unroll
    for (int tm = 0; tm < 2; ++tm) {
        const int dbase = dt * 64 + quadd + tm * 16 + rgrp;
        float4 g4 = *(const float4*)&gamma[dbase];
        float4 bb4 = *(const float4*)&beta[dbase];
        float4 m4 = *(const float4*)&mean[dbase];
        float4 v4 = *(const float4*)&var[dbase];
        float gf[4] = {g4.x, g4.y, g4.z, g4.w};
        float bf[4] = {bb4.x, bb4.y, bb4.z, bb4.w};
        float mf[4] = {m4.x, m4.y, m4.z, m4.w};
        float vf[4] = {v4.x, v4.y, v4.z, v4.w};
        float sc[4];
        #pragma unroll
        for (int r = 0; r < 4; ++r) sc[r] = rsqrtf(vf[r] + BN_EPS) * gf[r];

        #pragma unroll
        for (int tn = 0; tn < 2; ++tn) {
            const int p = pt * 64 + quadp + tn * 16 + lr;
            bf16x4 zq;
            #pragma unroll
            for (int r = 0; r < 4; ++r) {
                float n = (acc[tm][tn][r] - mf[r]) * sc[r] + bf[r];
                __bf16 hb = (__bf16)n;
                __bf16 lb = (__bf16)(n - (float)hb);
                size_t yi = ((size_t)b * C + dbase + r) * P + p;
                Yhi[yi] = hb;
                Ylo[yi] = lb;
                zq[r] = hb;
            }
            *(bf16x4*)&Zhi[((size_t)b * P + p) * C + dbase] = zq;
        }
    }
}

// ---------------------------------------------------------------------------
// Kernel 2 (FUSED v6 = round-6 loop + d-split for occupancy).
// Grid 1024: b = id&7 (XCD pin), ct = (id>>3)&63 (c-tile of 16), dh = id>>9.
// Each block: 8 d-windows of 64 (half of C). 4 waves; per it, wave w owns
// d-slice it*64 + w*16 — block covers the 64-d window simultaneously and the
// two barriers per it keep waves aligned (round-6 clean attn writes).
// out0: partial sums from the 2 dh-blocks combined via unsafeAtomicAdd
// (exactly 2 commutative f32 adds per element -> deterministic).
// No register hoists; __launch_bounds__(256,4) -> 4 blocks/CU, 16 waves/CU.
// ---------------------------------------------------------------------------
__global__ __launch_bounds__(256, 4) void attn_fused(
    const __bf16* __restrict__ Yhi, const __bf16* __restrict__ Ylo,
    const __bf16* __restrict__ Zhi, const float* __restrict__ gs_ptr,
    float* __restrict__ attn, float* __restrict__ out0)
{
    const int id = blockIdx.x;
    const int b  = id & 7;            // XCD pin (dispatch round-robins XCDs)
    const int ct = (id >> 3) & 63;    // 0..63
    const int dh = id >> 9;           // 0/1: d-half
    const int c0 = ct * 16;
    const int t = threadIdx.x, lane = t & 63, w = t >> 6;
    const int lr = lane & 15;
    const int lg = lane >> 4;
    const int lk = lg * 8;
    const int rgrp = lg * 4;
    const float scale = 1.0f / gs_ptr[0];

    __shared__ __bf16 Plds[8][16][72];   // [h][c16][d64 pad] = 18 KB
    __shared__ float Olds[64][20];       // transpose buffer = 5 KB

    f32x4 out_acc[8];
    #pragma unroll
    for (int h = 0; h < H; ++h) out_acc[h] = (f32x4){0.f, 0.f, 0.f, 0.f};

    const size_t cbase = ((size_t)b * C + c0 + lr) * P;   // c-side row (A)

    for (int it = 0; it < 8; ++it) {
        const int dwin0 = dh * 512 + it * 64;              // block's d-window
        const int dwin  = dwin0 + w * 16;                  // wave's d-slice
        const size_t dbase = ((size_t)b * C + dwin + lr) * P;  // d-side row (B)

        // ---- phase 1: scores 16c x 16d (this wave's d-slice), all 8 heads
        f32x4 sacc[8];
        #pragma unroll
        for (int h = 0; h < H; ++h) sacc[h] = (f32x4){0.f, 0.f, 0.f, 0.f};

        #pragma unroll
        for (int h = 0; h < H; ++h) {
            #pragma unroll
            for (int s = 0; s < 2; ++s) {
                const int col = h * 64 + s * 32 + lk;
                bf16x8 ch_ = *(const bf16x8*)&Yhi[cbase + col];
                bf16x8 cl_ = *(const bf16x8*)&Ylo[cbase + col];
                bf16x8 bh_ = *(const bf16x8*)&Yhi[dbase + col];
                bf16x8 bl_ = *(const bf16x8*)&Ylo[dbase + col];
                sacc[h] = __builtin_amdgcn_mfma_f32_16x16x32_bf16(ch_, bh_, sacc[h], 0, 0, 0);
                sacc[h] = __builtin_amdgcn_mfma_f32_16x16x32_bf16(ch_, bl_, sacc[h], 0, 0, 0);
                sacc[h] = __builtin_amdgcn_mfma_f32_16x16x32_bf16(cl_, bh_, sacc[h], 0, 0, 0);
            }
        }

        // ---- softmax over h per (c,d); write attn + P(bf16) to LDS ----
        const int dcol = dwin + lr;
        #pragma unroll
        for (int r = 0; r < 4; ++r) {
            const int c = c0 + rgrp + r;
            float v[8];
            float m = -1e30f;
            #pragma unroll
            for (int h = 0; h < H; ++h) {
                v[h] = sacc[h][r] * scale;
                m = fmaxf(m, v[h]);
            }
            float ssum = 0.f;
            #pragma unroll
            for (int h = 0; h < H; ++h) { v[h] = __expf(v[h] - m); ssum += v[h]; }
            float inv = 1.0f / ssum;
            #pragma unroll
            for (int h = 0; h < H; ++h) {
                float p = v[h] * inv;
                attn[(((size_t)(b * H + h) * C + c) * C) + dcol] = p;
                Plds[h][rgrp + r][w * 16 + lr] = (__bf16)p;
            }
        }
        __syncthreads();

        // ---- phase 2: PV partial for this d-window (hi-only P, hi-only V) ----
        #pragma unroll
        for (int h = 0; h < H; ++h) {
            const int p = h * 64 + w * 16 + lr;
            #pragma unroll
            for (int kh = 0; kh < 2; ++kh) {
                bf16x8 bv = *(const bf16x8*)&Zhi[((size_t)b * P + p) * C + dwin0 + kh * 32 + lk];
                bf16x8 a = *(const bf16x8*)&Plds[h][lr][kh * 32 + lk];
                out_acc[h] = __builtin_amdgcn_mfma_f32_16x16x32_bf16(a, bv, out_acc[h], 0, 0, 0);
            }
        }
        __syncthreads();
    }

    // ---- epilogue: per head, LDS transpose then atomic-add into out0 ----
    #pragma unroll
    for (int h = 0; h < H; ++h) {
        #pragma unroll
        for (int r = 0; r < 4; ++r)
            Olds[w * 16 + lr][rgrp + r] = out_acc[h][r];
        __syncthreads();
        {
            const int row = t >> 2;            // 0..63 (p within head)
            const int coff = (t & 3) * 4;      // 0..12
            f32x4 vv = *(const f32x4*)&Olds[row][coff];
            float* dst = &out0[((size_t)b * P + h * 64 + row) * C + c0 + coff];
            #pragma unroll
            for (int j = 0; j < 4; ++j) unsafeAtomicAdd(dst + j, vv[j]);
        }
        __syncthreads();
    }
}

extern "C" void kernel_launch(void* const* d_in, const int* in_sizes, int n_in,
                              void* d_out, int out_size, void* d_ws, size_t ws_size,
                              hipStream_t stream) {
    const float* x     = (const float*)d_in[0];
    const float* Wq    = (const float*)d_in[1];
    const float* gamma = (const float*)d_in[2];
    const float* beta  = (const float*)d_in[3];
    const float* mean  = (const float*)d_in[4];
    const float* var   = (const float*)d_in[5];
    const float* gs    = (const float*)d_in[6];

    float* out0 = (float*)d_out;                          // h: (B,P,C)
    float* attn = (float*)d_out + (size_t)B * P * C;      // attn: (B,H,C,C)

    const size_t NE = (size_t)B * C * P;                  // 4M elements
    __bf16* Yhi = (__bf16*)d_ws;                          // 8 MB
    __bf16* Ylo = Yhi + NE;                               // 8 MB
    __bf16* Zhi = Ylo + NE;                               // 8 MB

    // transient scratch in the attn-region tail (dead before attn is written)
    const size_t attn_elems = (size_t)B * H * C * C;
    __bf16* S = (__bf16*)(attn + (attn_elems - 5242880));
    __bf16* xhi = S;
    __bf16* xlo = xhi + (size_t)B * P * C;
    __bf16* whi = xlo + (size_t)B * P * C;
    __bf16* wlo = whi + (size_t)C * C;

    split_hi_lo<<<5120, 256, 0, stream>>>(x, Wq, xhi, xlo, whi, wlo);
    zero_out0<<<4096, 256, 0, stream>>>(out0);
    qkv_bn_mfma<<<dim3(16, 8, 8), 256, 0, stream>>>(xhi, xlo, whi, wlo,
                                                    gamma, beta, mean, var,
                                                    Yhi, Ylo, Zhi);
    attn_fused<<<1024, 256, 0, stream>>>(Yhi, Ylo, Zhi, gs, attn, out0);
}

// Round 11
// 354.148 us; speedup vs baseline: 1.5902x; 1.5243x over previous
//
#include <hip/hip_runtime.h>
#include <math.h>

#define B 8
#define P 512
#define C 1024
#define H 8
#define BN_EPS 1e-5f

typedef __attribute__((ext_vector_type(8))) __bf16 bf16x8;
typedef __attribute__((ext_vector_type(4))) __bf16 bf16x4;
typedef __attribute__((ext_vector_type(4))) float f32x4;

// ---------------------------------------------------------------------------
// Kernel 0: split x (B,P,C) and W (C,C) into hi/lo bf16. One float4/thread.
// ---------------------------------------------------------------------------
__global__ __launch_bounds__(256) void split_hi_lo(
    const float* __restrict__ x, const float* __restrict__ Wq,
    __bf16* __restrict__ xhi, __bf16* __restrict__ xlo,
    __bf16* __restrict__ whi, __bf16* __restrict__ wlo)
{
    const size_t NX4 = (size_t)B * P * C / 4;
    size_t idx = (size_t)blockIdx.x * 256 + threadIdx.x;
    float4 v;
    __bf16 *dh, *dl;
    size_t o;
    if (idx < NX4) {
        v = ((const float4*)x)[idx];
        dh = xhi; dl = xlo; o = idx * 4;
    } else {
        v = ((const float4*)Wq)[idx - NX4];
        dh = whi; dl = wlo; o = (idx - NX4) * 4;
    }
    float f[4] = {v.x, v.y, v.z, v.w};
    bf16x4 hv, lv;
    #pragma unroll
    for (int j = 0; j < 4; ++j) {
        __bf16 hb = (__bf16)f[j];
        hv[j] = hb;
        lv[j] = (__bf16)(f[j] - (float)hb);
    }
    *(bf16x4*)&dh[o] = hv;
    *(bf16x4*)&dl[o] = lv;
}

// ---------------------------------------------------------------------------
// Kernel 1: Y[b,d,p] = BN( sum_c W[d,c] * x[b,p,c] ) via split-bf16 MFMA.
// (unchanged — proven)
// ---------------------------------------------------------------------------
__global__ __launch_bounds__(256) void qkv_bn_mfma(
    const __bf16* __restrict__ xhi, const __bf16* __restrict__ xlo,
    const __bf16* __restrict__ whi, const __bf16* __restrict__ wlo,
    const float* __restrict__ gamma, const float* __restrict__ beta,
    const float* __restrict__ mean, const float* __restrict__ var,
    __bf16* __restrict__ Yhi, __bf16* __restrict__ Ylo, __bf16* __restrict__ Zhi)
{
    const int dt = blockIdx.x;   // 16
    const int pt = blockIdx.y;   // 8
    const int b  = blockIdx.z;   // 8
    const int t = threadIdx.x, lane = t & 63, wid = t >> 6;
    const int quadd = (wid >> 1) * 32, quadp = (wid & 1) * 32;
    const int lr = lane & 15, lk = (lane >> 4) * 8;

    const int drow0 = dt * 64 + quadd + lr;
    const size_t xrow0 = ((size_t)b * P + pt * 64 + quadp + lr) * C;

    f32x4 acc[2][2];
    #pragma unroll
    for (int tm = 0; tm < 2; ++tm)
        #pragma unroll
        for (int tn = 0; tn < 2; ++tn)
            acc[tm][tn] = (f32x4){0.f, 0.f, 0.f, 0.f};

    for (int c0 = 0; c0 < C; c0 += 32) {
        const int col = c0 + lk;
        bf16x8 ah[2], al[2], bh[2], bl[2];
        #pragma unroll
        for (int tm = 0; tm < 2; ++tm) {
            size_t ia = (size_t)(drow0 + tm * 16) * C + col;
            ah[tm] = *(const bf16x8*)&whi[ia];
            al[tm] = *(const bf16x8*)&wlo[ia];
        }
        #pragma unroll
        for (int tn = 0; tn < 2; ++tn) {
            size_t ib = xrow0 + (size_t)tn * 16 * C + col;
            bh[tn] = *(const bf16x8*)&xhi[ib];
            bl[tn] = *(const bf16x8*)&xlo[ib];
        }
        #pragma unroll
        for (int tm = 0; tm < 2; ++tm)
            #pragma unroll
            for (int tn = 0; tn < 2; ++tn) {
                acc[tm][tn] = __builtin_amdgcn_mfma_f32_16x16x32_bf16(ah[tm], bh[tn], acc[tm][tn], 0, 0, 0);
                acc[tm][tn] = __builtin_amdgcn_mfma_f32_16x16x32_bf16(ah[tm], bl[tn], acc[tm][tn], 0, 0, 0);
                acc[tm][tn] = __builtin_amdgcn_mfma_f32_16x16x32_bf16(al[tm], bh[tn], acc[tm][tn], 0, 0, 0);
            }
    }

    const int rgrp = (lane >> 4) * 4;
    #pragma unroll
    for (int tm = 0; tm < 2; ++tm) {
        const int dbase = dt * 64 + quadd + tm * 16 + rgrp;
        float4 g4 = *(const float4*)&gamma[dbase];
        float4 bb4 = *(const float4*)&beta[dbase];
        float4 m4 = *(const float4*)&mean[dbase];
        float4 v4 = *(const float4*)&var[dbase];
        float gf[4] = {g4.x, g4.y, g4.z, g4.w};
        float bf[4] = {bb4.x, bb4.y, bb4.z, bb4.w};
        float mf[4] = {m4.x, m4.y, m4.z, m4.w};
        float vf[4] = {v4.x, v4.y, v4.z, v4.w};
        float sc[4];
        #pragma unroll
        for (int r = 0; r < 4; ++r) sc[r] = rsqrtf(vf[r] + BN_EPS) * gf[r];

        #pragma unroll
        for (int tn = 0; tn < 2; ++tn) {
            const int p = pt * 64 + quadp + tn * 16 + lr;
            bf16x4 zq;
            #pragma unroll
            for (int r = 0; r < 4; ++r) {
                float n = (acc[tm][tn][r] - mf[r]) * sc[r] + bf[r];
                __bf16 hb = (__bf16)n;
                __bf16 lb = (__bf16)(n - (float)hb);
                size_t yi = ((size_t)b * C + dbase + r) * P + p;
                Yhi[yi] = hb;
                Ylo[yi] = lb;
                zq[r] = hb;
            }
            *(bf16x4*)&Zhi[((size_t)b * P + p) * C + dbase] = zq;
        }
    }
}

// ---------------------------------------------------------------------------
// Kernel 2 (FUSED v7 = round-6 base + store-drain-free barriers).
// Grid 512: b = id&7 (XCD pin), ct = id>>3 (64 c-tiles of 16). 4 waves.
// Per it: wave w owns d-slice it*64 + w*16 (block covers a 64-d window).
// Changes vs round 6 (210 µs measured):
//  1. Plds double-buffered -> ONE barrier per it (was 2).
//  2. In-loop barrier = s_waitcnt lgkmcnt(0) + raw s_barrier: attn stores
//     (vmcnt) are never drained in the loop — __syncthreads' vmcnt(0) was
//     forcing a full store-ack drain 32x per block (m97 barrier-drain).
//     Only cross-wave dependency in-loop is Plds (LDS) = lgkmcnt. Safe.
//  3. c-side hi fragments hoisted to registers (loop-invariant).
// Epilogue unchanged (direct stores, __syncthreads fine there).
// ---------------------------------------------------------------------------
__global__ __launch_bounds__(256, 2) void attn_fused(
    const __bf16* __restrict__ Yhi, const __bf16* __restrict__ Ylo,
    const __bf16* __restrict__ Zhi, const float* __restrict__ gs_ptr,
    float* __restrict__ attn, float* __restrict__ out0)
{
    const int id = blockIdx.x;
    const int b  = id & 7;            // XCD pin (dispatch round-robins XCDs)
    const int ct = id >> 3;           // 0..63
    const int c0 = ct * 16;
    const int t = threadIdx.x, lane = t & 63, w = t >> 6;
    const int lr = lane & 15;
    const int lg = lane >> 4;
    const int lk = lg * 8;
    const int rgrp = lg * 4;
    const float scale = 1.0f / gs_ptr[0];

    __shared__ __bf16 Plds[2][8][16][72];   // double-buffered: 36 KB
    __shared__ float Olds[64][20];          // transpose buffer = 5 KB

    // ---- hoist loop-invariant c-side hi fragments (64 VGPR) ----
    const size_t cbase = ((size_t)b * C + c0 + lr) * P;   // c-side row (A)
    bf16x8 chh[16];
    #pragma unroll
    for (int h = 0; h < H; ++h)
        #pragma unroll
        for (int s = 0; s < 2; ++s)
            chh[h * 2 + s] = *(const bf16x8*)&Yhi[cbase + h * 64 + s * 32 + lk];

    f32x4 out_acc[8];
    #pragma unroll
    for (int h = 0; h < H; ++h) out_acc[h] = (f32x4){0.f, 0.f, 0.f, 0.f};

    for (int it = 0; it < 16; ++it) {
        const int dwin0 = it * 64;                         // block's d-window
        const int dwin  = dwin0 + w * 16;                  // wave's d-slice
        const size_t dbase = ((size_t)b * C + dwin + lr) * P;  // d-side row (B)
        const int buf = it & 1;

        // ---- phase 1: scores 16c x 16d (this wave's d-slice), all 8 heads
        f32x4 sacc[8];
        #pragma unroll
        for (int h = 0; h < H; ++h) sacc[h] = (f32x4){0.f, 0.f, 0.f, 0.f};

        #pragma unroll
        for (int h = 0; h < H; ++h) {
            #pragma unroll
            for (int s = 0; s < 2; ++s) {
                const int col = h * 64 + s * 32 + lk;
                bf16x8 cl_ = *(const bf16x8*)&Ylo[cbase + col];
                bf16x8 bh_ = *(const bf16x8*)&Yhi[dbase + col];
                bf16x8 bl_ = *(const bf16x8*)&Ylo[dbase + col];
                sacc[h] = __builtin_amdgcn_mfma_f32_16x16x32_bf16(chh[h * 2 + s], bh_, sacc[h], 0, 0, 0);
                sacc[h] = __builtin_amdgcn_mfma_f32_16x16x32_bf16(chh[h * 2 + s], bl_, sacc[h], 0, 0, 0);
                sacc[h] = __builtin_amdgcn_mfma_f32_16x16x32_bf16(cl_, bh_, sacc[h], 0, 0, 0);
            }
        }

        // ---- softmax over h per (c,d); write attn + P(bf16) to LDS ----
        const int dcol = dwin + lr;
        #pragma unroll
        for (int r = 0; r < 4; ++r) {
            const int c = c0 + rgrp + r;
            float v[8];
            float m = -1e30f;
            #pragma unroll
            for (int h = 0; h < H; ++h) {
                v[h] = sacc[h][r] * scale;
                m = fmaxf(m, v[h]);
            }
            float ssum = 0.f;
            #pragma unroll
            for (int h = 0; h < H; ++h) { v[h] = __expf(v[h] - m); ssum += v[h]; }
            float inv = 1.0f / ssum;
            #pragma unroll
            for (int h = 0; h < H; ++h) {
                float p = v[h] * inv;
                attn[(((size_t)(b * H + h) * C + c) * C) + dcol] = p;
                Plds[buf][h][rgrp + r][w * 16 + lr] = (__bf16)p;
            }
        }

        // ---- LDS-only barrier: do NOT drain vmcnt (attn stores in flight) ----
        asm volatile("s_waitcnt lgkmcnt(0)" ::: "memory");
        __builtin_amdgcn_s_barrier();
        asm volatile("" ::: "memory");

        // ---- phase 2: PV partial for this d-window (hi-only P, hi-only V) ----
        #pragma unroll
        for (int h = 0; h < H; ++h) {
            const int p = h * 64 + w * 16 + lr;
            #pragma unroll
            for (int kh = 0; kh < 2; ++kh) {
                bf16x8 bv = *(const bf16x8*)&Zhi[((size_t)b * P + p) * C + dwin0 + kh * 32 + lk];
                bf16x8 a = *(const bf16x8*)&Plds[buf][h][lr][kh * 32 + lk];
                out_acc[h] = __builtin_amdgcn_mfma_f32_16x16x32_bf16(a, bv, out_acc[h], 0, 0, 0);
            }
        }
        // no trailing barrier: next it writes the other Plds buffer; reuse of
        // this buffer at it+2 is fenced by the barrier at it+1 (reads are
        // lgkm ops, covered by that barrier's lgkmcnt(0)).
    }

    // ---- epilogue: per head, LDS transpose then coalesced out0 store ----
    __syncthreads();
    #pragma unroll
    for (int h = 0; h < H; ++h) {
        #pragma unroll
        for (int r = 0; r < 4; ++r)
            Olds[w * 16 + lr][rgrp + r] = out_acc[h][r];
        __syncthreads();
        {
            const int row = t >> 2;            // 0..63 (p within head)
            const int coff = (t & 3) * 4;      // 0..12
            f32x4 vv = *(const f32x4*)&Olds[row][coff];
            *(f32x4*)&out0[((size_t)b * P + h * 64 + row) * C + c0 + coff] = vv;
        }
        __syncthreads();
    }
}

extern "C" void kernel_launch(void* const* d_in, const int* in_sizes, int n_in,
                              void* d_out, int out_size, void* d_ws, size_t ws_size,
                              hipStream_t stream) {
    const float* x     = (const float*)d_in[0];
    const float* Wq    = (const float*)d_in[1];
    const float* gamma = (const float*)d_in[2];
    const float* beta  = (const float*)d_in[3];
    const float* mean  = (const float*)d_in[4];
    const float* var   = (const float*)d_in[5];
    const float* gs    = (const float*)d_in[6];

    float* out0 = (float*)d_out;                          // h: (B,P,C)
    float* attn = (float*)d_out + (size_t)B * P * C;      // attn: (B,H,C,C)

    const size_t NE = (size_t)B * C * P;                  // 4M elements
    __bf16* Yhi = (__bf16*)d_ws;                          // 8 MB
    __bf16* Ylo = Yhi + NE;                               // 8 MB
    __bf16* Zhi = Ylo + NE;                               // 8 MB

    // transient scratch in the attn-region tail (dead before attn is written)
    const size_t attn_elems = (size_t)B * H * C * C;
    __bf16* S = (__bf16*)(attn + (attn_elems - 5242880));
    __bf16* xhi = S;
    __bf16* xlo = xhi + (size_t)B * P * C;
    __bf16* whi = xlo + (size_t)B * P * C;
    __bf16* wlo = whi + (size_t)C * C;

    split_hi_lo<<<5120, 256, 0, stream>>>(x, Wq, xhi, xlo, whi, wlo);
    qkv_bn_mfma<<<dim3(16, 8, 8), 256, 0, stream>>>(xhi, xlo, whi, wlo,
                                                    gamma, beta, mean, var,
                                                    Yhi, Ylo, Zhi);
    attn_fused<<<512, 256, 0, stream>>>(Yhi, Ylo, Zhi, gs, attn, out0);
}